// Round 5
// baseline (229.612 us; speedup 1.0000x reference)
//
#include <hip/hip_runtime.h>
#include <math.h>

// ---------------------------------------------------------------------------
// Round 5: xpath with T3/T4 pipelined weight staging (double-buffered Ws,
// counted-vmcnt raw-barrier sync) — staging overlaps MFMA, no vmcnt(0) drain
// between stage and compute.
//   prep:  proj_w/mw1/mw2 fp32->bf16 ; bias_table -> biasPb[h][n][lr][8] bf16
//   A: ln_qkv: LN(q,k,v) + window partition -> qw/kw/vw bf16 [512][128][256]
//   B: attn per (window,head), 40KB LDS, swizzled Ps/Vt, bf16 bias -> ao
//   X: xpath per WINDOW (512 blocks, 512 thr = 8 waves, 160KB LDS):
//      28-step unified pipeline: step s stages step s+1's weight k-slice into
//      buf[(s+1)&1] then MFMAs from buf[s&1]; one s_barrier+vmcnt(0) per step
//      AFTER compute (guide §5.5 T3 minimum 2-phase).
//
// Workspace layout unchanged from R3/R4.
// ---------------------------------------------------------------------------

typedef __attribute__((ext_vector_type(8))) short short8;
typedef __attribute__((ext_vector_type(4))) short shortx4;
typedef __attribute__((ext_vector_type(4))) float floatx4;

#define MFMA16(a, b, c) __builtin_amdgcn_mfma_f32_16x16x32_bf16((a), (b), (c), 0, 0, 0)
#define ATT_SCALE 0.17677669529663689f /* 32^-0.5 */

// stage -> [compute] -> PIPE_SYNC: staged loads had the MFMA phase to land.
#define PIPE_SYNC()                                  \
  do {                                               \
    asm volatile("s_waitcnt vmcnt(0)" ::: "memory"); \
    __builtin_amdgcn_s_barrier();                    \
    __builtin_amdgcn_sched_barrier(0);               \
  } while (0)

__device__ __forceinline__ short f2bf(float f) {
  unsigned u = __float_as_uint(f);
  u += 0x7fffu + ((u >> 16) & 1u);
  return (short)(u >> 16);
}
__device__ __forceinline__ float bf2f(short s) {
  return __uint_as_float(((unsigned)(unsigned short)s) << 16);
}
__device__ __forceinline__ void gl2lds(const short* g, short* l) {
  __builtin_amdgcn_global_load_lds((const __attribute__((address_space(1))) void*)(g),
                                   (__attribute__((address_space(3))) void*)(l), 16, 0, 0);
}

// ---------------------------------------------------------------------------
// prep kernels
// ---------------------------------------------------------------------------
__global__ void cvt_kernel(const float* __restrict__ src, short* __restrict__ dst, int n) {
  int i = blockIdx.x * 256 + threadIdx.x;
  if (i < n) dst[i] = f2bf(src[i]);
}

__global__ void biasprep_kernel(const float* __restrict__ table, short* __restrict__ biasPb) {
  int idx = blockIdx.x * 256 + threadIdx.x;  // [0, 131072)
  int h = idx >> 14;
  int n = (idx >> 7) & 127;
  int lr = (idx >> 3) & 15;
  int c = idx & 7;
  int m = 16 * c + lr;
  int t1 = n >> 6, h1 = (n >> 3) & 7, w1 = n & 7;
  int t2 = m >> 6, h2 = (m >> 3) & 7, w2 = m & 7;
  int ridx = (t1 - t2 + 1) * 225 + (h1 - h2 + 7) * 15 + (w1 - w2 + 7);
  biasPb[idx] = f2bf(table[ridx * 8 + h]);
}

// ---------------------------------------------------------------------------
// Kernel A: LN + window partition, fp32 -> bf16 window layout. One wave/token.
// ---------------------------------------------------------------------------
__global__ __launch_bounds__(256) void ln_qkv_kernel(
    const float* __restrict__ q, const float* __restrict__ k, const float* __restrict__ v,
    const float* __restrict__ gq, const float* __restrict__ bq,
    const float* __restrict__ gk, const float* __restrict__ bk,
    const float* __restrict__ gv, const float* __restrict__ bv,
    short* __restrict__ qw, short* __restrict__ kw, short* __restrict__ vw) {
  const int wv = threadIdx.x >> 6, l = threadIdx.x & 63;
  const int tok = blockIdx.x * 4 + wv;
  const int which = blockIdx.y;
  const float* src = (which == 0) ? q : ((which == 1) ? k : v);
  const float* gg  = (which == 0) ? gq : ((which == 1) ? gk : gv);
  const float* bb  = (which == 0) ? bq : ((which == 1) ? bk : bv);
  short* dst       = (which == 0) ? qw : ((which == 1) ? kw : vw);

  float4 xv = *(const float4*)(src + (size_t)tok * 256 + l * 4);
  float s1 = xv.x + xv.y + xv.z + xv.w;
  float s2 = xv.x * xv.x + xv.y * xv.y + xv.z * xv.z + xv.w * xv.w;
#pragma unroll
  for (int off = 1; off < 64; off <<= 1) {
    s1 += __shfl_xor(s1, off);
    s2 += __shfl_xor(s2, off);
  }
  float mean = s1 * (1.0f / 256.0f);
  float var = s2 * (1.0f / 256.0f) - mean * mean;
  float inv = rsqrtf(var + 1e-5f);

  int b_ = tok >> 15, rem = tok & 32767;
  int t = rem >> 12, hh = (rem >> 6) & 63, ww = rem & 63;
  int wi = ((b_ * 4 + (t >> 1)) * 8 + (hh >> 3)) * 8 + (ww >> 3);
  int n = ((t & 1) << 6) | ((hh & 7) << 3) | (ww & 7);

  float4 g4 = *(const float4*)(gg + l * 4);
  float4 b4 = *(const float4*)(bb + l * 4);
  shortx4 o;
  o[0] = f2bf((xv.x - mean) * inv * g4.x + b4.x);
  o[1] = f2bf((xv.y - mean) * inv * g4.y + b4.y);
  o[2] = f2bf((xv.z - mean) * inv * g4.z + b4.z);
  o[3] = f2bf((xv.w - mean) * inv * g4.w + b4.w);
  *(shortx4*)(dst + ((size_t)wi * 128 + n) * 256 + l * 4) = o;
}

// ---------------------------------------------------------------------------
// Kernel B: windowed attention, one block per (window, head), 4 waves, 40KB LDS.
// ---------------------------------------------------------------------------
__global__ __launch_bounds__(256, 4) void attn_kernel(
    const short* __restrict__ qw, const short* __restrict__ kw, const short* __restrict__ vw,
    const short* __restrict__ biasPb, short* __restrict__ ao) {
  __shared__ union SU {
    struct { short Qs[128][40]; short Ks[128][40]; } qk;
    short Ps[128 * 128];  // XOR-swizzled
  } su;
  __shared__ short Vt[32 * 128];  // V^T, XOR-swizzled

  const int wi = blockIdx.x, h = blockIdx.y, tid = threadIdx.x;
  const size_t base = (size_t)wi * 128 * 256 + h * 32;

#pragma unroll
  for (int i = 0; i < 2; ++i) {
    int idx = tid + 256 * i;        // 0..511
    int m = idx >> 2, c = idx & 3;  // token row, 8-elem unit
    *(short8*)&su.qk.Qs[m][c * 8] = *(const short8*)(qw + base + (size_t)m * 256 + c * 8);
    *(short8*)&su.qk.Ks[m][c * 8] = *(const short8*)(kw + base + (size_t)m * 256 + c * 8);
    short8 vv = *(const short8*)(vw + base + (size_t)m * 256 + c * 8);
#pragma unroll
    for (int e = 0; e < 8; ++e) {
      int d = c * 8 + e;
      Vt[d * 128 + (((m >> 3) ^ (d & 7)) << 3) + (m & 7)] = vv[e];
    }
  }
  __syncthreads();

  const int wvv = tid >> 6, l = tid & 63, lr = l & 15, g = l >> 4;
  const floatx4 zf = {0.f, 0.f, 0.f, 0.f};

  short8 aq0 = *(const short8*)&su.qk.Qs[32 * wvv + lr][g * 8];
  short8 aq1 = *(const short8*)&su.qk.Qs[32 * wvv + 16 + lr][g * 8];

  floatx4 s[2][8];
#pragma unroll
  for (int c = 0; c < 8; ++c) {
    short8 bk8 = *(const short8*)&su.qk.Ks[16 * c + lr][g * 8];
    s[0][c] = MFMA16(aq0, bk8, zf);
    s[1][c] = MFMA16(aq1, bk8, zf);
  }
  __syncthreads();  // Qs/Ks dead -> Ps region reusable

  const int lr7 = lr & 7;
#pragma unroll
  for (int r = 0; r < 2; ++r) {
#pragma unroll
    for (int j = 0; j < 4; ++j) {
      int n = 32 * wvv + 16 * r + 4 * g + j;
      short8 bv8 = *(const short8*)(biasPb + ((size_t)(h * 128 + n) * 16 + lr) * 8);
      float mx = -1e30f;
#pragma unroll
      for (int c = 0; c < 8; ++c) {
        float val = s[r][c][j] * ATT_SCALE + bf2f(bv8[c]);
        s[r][c][j] = val;
        mx = fmaxf(mx, val);
      }
#pragma unroll
      for (int off = 1; off < 16; off <<= 1) mx = fmaxf(mx, __shfl_xor(mx, off));
      float sum = 0.f;
#pragma unroll
      for (int c = 0; c < 8; ++c) {
        float e = __expf(s[r][c][j] - mx);
        s[r][c][j] = e;
        sum += e;
      }
#pragma unroll
      for (int off = 1; off < 16; off <<= 1) sum += __shfl_xor(sum, off);
      float invs = 1.0f / sum;
      int n7 = n & 7;
#pragma unroll
      for (int c = 0; c < 8; ++c) {
        int col = 16 * c + lr;
        su.Ps[n * 128 + (((col >> 3) ^ n7) << 3) + (col & 7)] = f2bf(s[r][c][j] * invs);
      }
    }
  }
  // each wave reads only its own 32 P rows below -> no barrier

  floatx4 o00 = zf, o01 = zf, o10 = zf, o11 = zf;
  const int ra0 = 32 * wvv + lr, ra1 = ra0 + 16;
#pragma unroll
  for (int ks = 0; ks < 4; ++ks) {
    int ulog = ks * 4 + g;
    short8 pa0 = *(const short8*)&su.Ps[ra0 * 128 + ((ulog ^ (ra0 & 7)) << 3)];
    short8 pa1 = *(const short8*)&su.Ps[ra1 * 128 + ((ulog ^ (ra1 & 7)) << 3)];
    short8 vb0 = *(const short8*)&Vt[lr * 128 + ((ulog ^ lr7) << 3)];
    short8 vb1 = *(const short8*)&Vt[(16 + lr) * 128 + ((ulog ^ lr7) << 3)];
    o00 = MFMA16(pa0, vb0, o00);
    o01 = MFMA16(pa0, vb1, o01);
    o10 = MFMA16(pa1, vb0, o10);
    o11 = MFMA16(pa1, vb1, o11);
  }
#pragma unroll
  for (int j = 0; j < 4; ++j) {
    int n0 = 32 * wvv + 4 * g + j;
    int n1 = n0 + 16;
    size_t rb0 = ((size_t)wi * 128 + n0) * 256 + h * 32;
    size_t rb1 = ((size_t)wi * 128 + n1) * 256 + h * 32;
    ao[rb0 + lr] = f2bf(o00[j]);
    ao[rb0 + 16 + lr] = f2bf(o01[j]);
    ao[rb1 + lr] = f2bf(o10[j]);
    ao[rb1 + 16 + lr] = f2bf(o11[j]);
  }
}

// ---------------------------------------------------------------------------
// Kernel X: fused x-path, pipelined. One block per WINDOW, 512 thr = 8 waves.
// LDS: Ws0/Ws1 2x32KB (dbuf weight k-slices) | XL 64KB | H1 32KB = 160KB.
// 28 steps: proj k0..k3, then per qt {mlp1 k0..k3, mlp2 k0..k1}.
// Step s: stage step s+1 into buf[(s+1)&1]; MFMA from buf[s&1]; PIPE_SYNC.
// ---------------------------------------------------------------------------
__global__ __launch_bounds__(512, 1) void xpath_kernel(
    const short* __restrict__ ao, const short* __restrict__ wp,
    const float* __restrict__ proj_b, const float* __restrict__ vin,
    const float* __restrict__ g2, const float* __restrict__ b2,
    const short* __restrict__ w1, const float* __restrict__ mb1,
    const short* __restrict__ w2, const float* __restrict__ mb2,
    float* __restrict__ out) {
  __shared__ short Ws0[256 * 64];  // 32 KB (buf 0)
  __shared__ short Ws1[256 * 64];  // 32 KB (buf 1)
  __shared__ short XL[128 * 256];  // 64 KB, XOR-swizzled
  __shared__ short H1[128 * 128];  // 32 KB, XOR-swizzled

  const int tid = threadIdx.x;
  const int w = tid >> 6, l = tid & 63, lr = l & 15, g = l >> 4;
  const int li = l >> 3, u = l & 7;
  const int swz = ((u ^ li) << 3);
  const int s0 = ((g ^ (lr & 7)) << 3);
  const int s1 = (((4 + g) ^ (lr & 7)) << 3);
  const floatx4 zf = {0.f, 0.f, 0.f, 0.f};
  const int bx = blockIdx.x;    // window index
  const int r16 = 16 * w + lr;  // local A-frag row
  const size_t grow = (size_t)bx * 128;

  // stage helpers (LDS dest wave-uniform; per-lane swizzle on GLOBAL side)
  auto stP = [&](short* dst, int k0) {
#pragma unroll
    for (int i = 0; i < 4; ++i) {
      int c = w + 8 * i;
      gl2lds(wp + (size_t)(8 * c + li) * 256 + k0 + swz, dst + c * 512);
    }
  };
  auto st1 = [&](short* dst, int qt, int k0) {
#pragma unroll
    for (int i = 0; i < 2; ++i) {
      int c = w + 8 * i;
      gl2lds(w1 + (size_t)(qt * 128 + 8 * c + li) * 256 + k0 + swz, dst + c * 512);
    }
  };
  auto st2 = [&](short* dst, int qt, int k0) {
#pragma unroll
    for (int i = 0; i < 4; ++i) {
      int c = w + 8 * i;
      gl2lds(w2 + (size_t)(8 * c + li) * 512 + qt * 128 + k0 + swz, dst + c * 512);
    }
  };
  auto mm16 = [&](const short* Wb, short8 a0, short8 a1, floatx4* acc) {
#pragma unroll
    for (int ct = 0; ct < 16; ++ct) {
      int rb = ct * 16 + lr;
      acc[ct] = MFMA16(a0, *(const short8*)&Wb[rb * 64 + s0], acc[ct]);
      acc[ct] = MFMA16(a1, *(const short8*)&Wb[rb * 64 + s1], acc[ct]);
    }
  };
  auto mm8 = [&](const short* Wb, short8 a0, short8 a1, floatx4* acc) {
#pragma unroll
    for (int ct = 0; ct < 8; ++ct) {
      int rb = ct * 16 + lr;
      acc[ct] = MFMA16(a0, *(const short8*)&Wb[rb * 64 + s0], acc[ct]);
      acc[ct] = MFMA16(a1, *(const short8*)&Wb[rb * 64 + s1], acc[ct]);
    }
  };

  // preload all proj A-frags (issued earliest; compiler waits only these 8)
  short8 pa[8];
#pragma unroll
  for (int t = 0; t < 4; ++t) {
    pa[2 * t] = *(const short8*)(ao + (grow + r16) * 256 + 64 * t + g * 8);
    pa[2 * t + 1] = *(const short8*)(ao + (grow + r16) * 256 + 64 * t + 32 + g * 8);
  }

  floatx4 acc1[16];
#pragma unroll
  for (int i = 0; i < 16; ++i) acc1[i] = zf;

  // ---- pipeline prologue ----
  stP(Ws0, 0);
  PIPE_SYNC();

  // ---- P1: proj GEMM, steps 0..3 ----
  stP(Ws1, 64);
  mm16(Ws0, pa[0], pa[1], acc1);
  PIPE_SYNC();
  stP(Ws0, 128);
  mm16(Ws1, pa[2], pa[3], acc1);
  PIPE_SYNC();
  stP(Ws1, 192);
  mm16(Ws0, pa[4], pa[5], acc1);
  PIPE_SYNC();
  st1(Ws0, 0, 0);  // stage step 4 = mlp1 qt0 k0
  mm16(Ws1, pa[6], pa[7], acc1);
  PIPE_SYNC();

  // ---- epilogue: x = acc1 + proj_b + v(residual); LN2 -> XL (bf16) ----
  int sidx4[4];
  float xr[16][4];
  {
    const int wb = bx & 7, hb = (bx >> 3) & 7, tt = (bx >> 6) & 3, b_ = bx >> 8;
#pragma unroll
    for (int j = 0; j < 4; ++j) {
      int row = 16 * w + 4 * g + j;  // local row == pos in window (0..127)
      int t = tt * 2 + (row >> 6), hh = hb * 8 + ((row >> 3) & 7), ww2 = wb * 8 + (row & 7);
      int sidx = ((b_ * 8 + t) * 64 + hh) * 64 + ww2;
      sidx4[j] = sidx;
      float ss1 = 0.f, ss2 = 0.f;
#pragma unroll
      for (int ct = 0; ct < 16; ++ct) {
        int col = ct * 16 + lr;
        float val = acc1[ct][j] + proj_b[col] + vin[(size_t)sidx * 256 + col];
        xr[ct][j] = val;
        ss1 += val;
        ss2 += val * val;
      }
#pragma unroll
      for (int off = 1; off < 16; off <<= 1) {
        ss1 += __shfl_xor(ss1, off);
        ss2 += __shfl_xor(ss2, off);
      }
      float mean = ss1 * (1.0f / 256.0f);
      float var = ss2 * (1.0f / 256.0f) - mean * mean;
      float inv = rsqrtf(var + 1e-5f);
      int r7 = row & 7;
#pragma unroll
      for (int ct = 0; ct < 16; ++ct) {
        int col = ct * 16 + lr;
        float xl = (xr[ct][j] - mean) * inv * g2[col] + b2[col];
        int uu = col >> 3;
        XL[row * 256 + (((uu & 24) | ((uu & 7) ^ r7)) << 3) + (col & 7)] = f2bf(xl);
      }
    }
  }
  // per-wave XL rows; same-wave ds ordering -> no barrier needed here

  // ---- P2: per qt {mlp1 k0..k3 (steps par 0,1,0,1), mlp2 k0..k1 (0,1)} ----
  floatx4 acc3[16];
#pragma unroll
  for (int i = 0; i < 16; ++i) acc3[i] = zf;

  for (int qt = 0; qt < 4; ++qt) {
    floatx4 acc2[8];
#pragma unroll
    for (int i = 0; i < 8; ++i) acc2[i] = zf;
    const int xb = r16 * 256, x7 = r16 & 7;
    const int h1b = r16 * 128;

    // mlp1 k0 (reads buf0, staged in previous step)
    st1(Ws1, qt, 64);
    mm8(Ws0, *(const short8*)&XL[xb + 0 + ((g ^ x7) << 3)],
        *(const short8*)&XL[xb + 0 + (((4 + g) ^ x7) << 3)], acc2);
    PIPE_SYNC();
    // mlp1 k1
    st1(Ws0, qt, 128);
    mm8(Ws1, *(const short8*)&XL[xb + 64 + ((g ^ x7) << 3)],
        *(const short8*)&XL[xb + 64 + (((4 + g) ^ x7) << 3)], acc2);
    PIPE_SYNC();
    // mlp1 k2
    st1(Ws1, qt, 192);
    mm8(Ws0, *(const short8*)&XL[xb + 128 + ((g ^ x7) << 3)],
        *(const short8*)&XL[xb + 128 + (((4 + g) ^ x7) << 3)], acc2);
    PIPE_SYNC();
    // mlp1 k3 ; stage mlp2 k0
    st2(Ws0, qt, 0);
    mm8(Ws1, *(const short8*)&XL[xb + 192 + ((g ^ x7) << 3)],
        *(const short8*)&XL[xb + 192 + (((4 + g) ^ x7) << 3)], acc2);
    PIPE_SYNC();

    // GELU -> H1 (per-wave rows; same-wave ordering)
#pragma unroll
    for (int ct = 0; ct < 8; ++ct) {
      int col = ct * 16 + lr;
      float bias = mb1[qt * 128 + col];
#pragma unroll
      for (int j = 0; j < 4; ++j) {
        int row = 16 * w + 4 * g + j;
        float val = acc2[ct][j] + bias;
        float ge = 0.5f * val * (1.0f + erff(val * 0.70710678118654752f));
        int uu = col >> 3;
        H1[row * 128 + (((uu & 8) | ((uu & 7) ^ (row & 7))) << 3) + (col & 7)] = f2bf(ge);
      }
    }

    // mlp2 k0 ; stage mlp2 k1
    st2(Ws1, qt, 64);
    mm16(Ws0, *(const short8*)&H1[h1b + 0 + ((g ^ x7) << 3)],
         *(const short8*)&H1[h1b + 0 + (((4 + g) ^ x7) << 3)], acc3);
    PIPE_SYNC();
    // mlp2 k1 ; stage next qt's mlp1 k0 (unless last)
    if (qt < 3) st1(Ws0, qt + 1, 0);
    mm16(Ws1, *(const short8*)&H1[h1b + 64 + ((g ^ x7) << 3)],
         *(const short8*)&H1[h1b + 64 + (((4 + g) ^ x7) << 3)], acc3);
    PIPE_SYNC();
  }

  // ---- final: out = x + mlp2 + mb2 (spatial scatter) ----
#pragma unroll
  for (int ct = 0; ct < 16; ++ct) {
    int col = ct * 16 + lr;
    float bias = mb2[col];
#pragma unroll
    for (int j = 0; j < 4; ++j)
      out[(size_t)sidx4[j] * 256 + col] = xr[ct][j] + acc3[ct][j] + bias;
  }
}

// ---------------------------------------------------------------------------
extern "C" void kernel_launch(void* const* d_in, const int* in_sizes, int n_in,
                              void* d_out, int out_size, void* d_ws, size_t ws_size,
                              hipStream_t stream) {
  const float* q = (const float*)d_in[0];
  const float* k = (const float*)d_in[1];
  const float* v = (const float*)d_in[2];
  const float* gq = (const float*)d_in[3];
  const float* bq = (const float*)d_in[4];
  const float* gk = (const float*)d_in[5];
  const float* bk = (const float*)d_in[6];
  const float* gv = (const float*)d_in[7];
  const float* bv = (const float*)d_in[8];
  const float* bias_table = (const float*)d_in[9];
  const float* proj_w = (const float*)d_in[10];
  const float* proj_b = (const float*)d_in[11];
  const float* g2 = (const float*)d_in[12];
  const float* b2 = (const float*)d_in[13];
  const float* mw1 = (const float*)d_in[14];
  const float* mb1 = (const float*)d_in[15];
  const float* mw2 = (const float*)d_in[16];
  const float* mb2 = (const float*)d_in[17];

  char* ws = (char*)d_ws;
  short* qw = (short*)(ws + 0);
  short* kw = (short*)(ws + 33554432);
  short* vw = (short*)(ws + 67108864);
  short* ao = (short*)(ws + 100663296);
  short* wp = (short*)(ws + 167772160);
  short* w1 = (short*)(ws + 167903232);
  short* w2 = (short*)(ws + 168165376);
  short* biasPb = (short*)(ws + 168427520);

  cvt_kernel<<<256, 256, 0, stream>>>(proj_w, wp, 65536);
  cvt_kernel<<<512, 256, 0, stream>>>(mw1, w1, 131072);
  cvt_kernel<<<512, 256, 0, stream>>>(mw2, w2, 131072);
  biasprep_kernel<<<512, 256, 0, stream>>>(bias_table, biasPb);

  ln_qkv_kernel<<<dim3(16384, 3), 256, 0, stream>>>(q, k, v, gq, bq, gk, bk, gv, bv, qw, kw, vw);

  attn_kernel<<<dim3(512, 8), 256, 0, stream>>>(qw, kw, vw, biasPb, ao);

  xpath_kernel<<<512, 512, 0, stream>>>(ao, wp, proj_b, v, g2, b2, w1, mb1, w2, mb2,
                                        (float*)d_out);
}